// Round 8
// baseline (42812.039 us; speedup 1.0000x reference)
//
#include <hip/hip_runtime.h>
#include <hip/hip_bf16.h>

typedef __hip_bfloat16 bf16;

#define B_    4
#define L_    4096
#define K_    12
#define H_    64
#define ZC_   780        /* MEM + K */
#define NCH_  1548       /* 12 den + 768 re + 768 im */

__device__ __forceinline__ float softplusf(float x){ return log1pf(__expf(x)); }
__device__ __forceinline__ float sigmoidf(float x){ return 1.f / (1.f + __expf(-x)); }

// dtype probe: score_scale == ones; f32 1.0 -> 0x3F800000
__global__ void probe_k(const unsigned* __restrict__ ss, int* __restrict__ md)
{
    if (threadIdx.x == 0 && blockIdx.x == 0) {
        unsigned w = ss[0];
        int m = 0;                           // 0 = f32 (expected)
        if      (w == 0x3F803F80u) m = 1;    // bf16 pair
        else if (w == 0x3C003C00u) m = 2;    // f16 pair
        else if (w == 0x00000000u) m = 3;    // f64 low word
        else if (w != 0x3F800000u) m = 4;    // unknown
        md[0] = m;
    }
}

__global__ void fillf_k(float* __restrict__ p, long n, float v)
{
    for (long i = (long)blockIdx.x * blockDim.x + threadIdx.x; i < n;
         i += (long)gridDim.x * blockDim.x) p[i] = v;
}
// if *md != 0, overwrite out with 4000+mode (diagnostic)
__global__ void guard_k(const int* __restrict__ md, float* __restrict__ p, long n)
{
    const int m = *md;
    if (m == 0) return;
    for (long i = (long)blockIdx.x * blockDim.x + threadIdx.x; i < n;
         i += (long)gridDim.x * blockDim.x) p[i] = 4000.f + m;
}

// ---------------------------------------------------------------------------
// Naive f32 GEMM: C[M,N] = A @ B (+C if ACC). One thread per C element,
// grid-stride. Optional batching via blockIdx.y with ELEMENT strides sA/sB/sC.
// ---------------------------------------------------------------------------
template<bool ACC>
__global__ __launch_bounds__(256) void ngemm(
    const float* __restrict__ A, const float* __restrict__ B, float* __restrict__ C,
    int M, int N, int Kd, int lda, int ldb, int ldc, long sA, long sB, long sC)
{
    const float* Ab = A + (long)blockIdx.y * sA;
    const float* Bb = B + (long)blockIdx.y * sB;
    float*       Cb = C + (long)blockIdx.y * sC;
    const long MN = (long)M * N;
    for (long t = (long)blockIdx.x * blockDim.x + threadIdx.x; t < MN;
         t += (long)gridDim.x * blockDim.x) {
        const int mi = (int)(t / N), ni = (int)(t % N);
        const float* ar = Ab + (long)mi * lda;
        const float* bc = Bb + ni;
        float acc = 0.f;
        for (int kk = 0; kk < Kd; kk++) acc += ar[kk] * bc[(long)kk * ldb];
        const long ci = (long)mi * ldc + ni;
        if (ACC) Cb[ci] += acc; else Cb[ci] = acc;
    }
}

// conv: ZCo[r, c] = sum_i ck[i][c] * Zs[r+i][c],  Zs row r <-> global l0-3+r
__global__ void conv_k(const float* __restrict__ Zs, const float* __restrict__ ck,
                       float* __restrict__ ZCo, int rows)
{
    const long n = (long)rows * ZC_;
    for (long t = (long)blockIdx.x * blockDim.x + threadIdx.x; t < n;
         t += (long)gridDim.x * blockDim.x) {
        const int r = (int)(t / ZC_), c = (int)(t % ZC_);
        float v = ck[0 * ZC_ + c] * Zs[(long)r * ZC_ + c]
                + ck[1 * ZC_ + c] * Zs[(long)(r + 1) * ZC_ + c]
                + ck[2 * ZC_ + c] * Zs[(long)(r + 2) * ZC_ + c]
                + ck[3 * ZC_ + c] * Zs[(long)(r + 3) * ZC_ + c];
        ZCo[t] = v;
    }
}

// elementwise -> MERG[r, ch]: ch<12: p_w(k=ch); 12..780: re; 780..1548: im
__global__ void elem_k(const float* __restrict__ ZCo,
                       const float* __restrict__ theta_raw,
                       const float* __restrict__ decay,
                       const float* __restrict__ ssc,
                       float* __restrict__ MERG, int rows, int l0)
{
    const long n = (long)rows * NCH_;
    for (long t = (long)blockIdx.x * blockDim.x + threadIdx.x; t < n;
         t += (long)gridDim.x * blockDim.x) {
        const int r = (int)(t / NCH_), ch = (int)(t % NCH_);
        const int l = l0 + r;
        float v;
        if (ch < K_) {
            const int k = ch;
            const float sraw = ZCo[(long)r * ZC_ + 768 + k];
            const float lp = fminf(fmaxf(ssc[k] * sraw, -20.f), 20.f);
            v = __expf(lp - softplusf(decay[k]) * (float)(L_ - 1 - l));
        } else {
            const int c2 = (ch < 780) ? (ch - 12) : (ch - 780);
            const int k = c2 >> 6, h = c2 & 63;
            const float kval = ZCo[(long)r * ZC_ + c2];
            const float sraw = ZCo[(long)r * ZC_ + 768 + k];
            const float lp = fminf(fmaxf(ssc[k] * sraw, -20.f), 20.f);
            const float pw = __expf(lp - softplusf(decay[k]) * (float)(L_ - 1 - l));
            const float th = softplusf(theta_raw[k * 64 + h]) + 0.001f;
            const float phi = tanhf(kval) * th;
            float sn, cn; __sincosf(phi, &sn, &cn);
            v = kval * pw * ((ch < 780) ? cn : sn);
        }
        MERG[t] = v;
    }
}

// sequential in-place inclusive cumsum over rows, with carry across sections
__global__ void cumsum_k(float* __restrict__ MERG, float* __restrict__ carry,
                         int rows)
{
    const int ch = blockIdx.x * blockDim.x + threadIdx.x;
    if (ch >= NCH_) return;
    float run = carry[ch];
    for (int r = 0; r < rows; r++) {
        run += MERG[(long)r * NCH_ + ch];
        MERG[(long)r * NCH_ + ch] = run;
    }
    carry[ch] = run;
}

// OUTA[r, k*128 + {h, 64+h}] from cumsummed MERG + Q + G
__global__ void outa_k(const float* __restrict__ MERG, const float* __restrict__ Q,
                       const float* __restrict__ G, const float* __restrict__ nsc,
                       const float* __restrict__ bg, float* __restrict__ OUTA,
                       int rows)
{
    const long n = (long)rows * K_ * H_;
    for (long t = (long)blockIdx.x * blockDim.x + threadIdx.x; t < n;
         t += (long)gridDim.x * blockDim.x) {
        const int h = (int)(t & 63);
        const int k = (int)((t >> 6) % K_);
        const int r = (int)(t / (K_ * H_));
        const float den = MERG[(long)r * NCH_ + k];
        const float invd = 1.f / fmaxf(den, 1e-4f);
        const float sre = MERG[(long)r * NCH_ + 12 + k * 64 + h] * invd;
        const float sim = MERG[(long)r * NCH_ + 780 + k * 64 + h] * invd;
        const int kq = k >> 1;
        const float qr = Q[(long)r * 768 + (kq * 64 + h) * 2];
        const float qi = Q[(long)r * 768 + (kq * 64 + h) * 2 + 1];
        const float gate = sigmoidf(G[(long)r * K_ + k] + bg[k]);
        const float s2 = nsc[k * 64 + h] * gate;
        OUTA[(long)r * 1536 + k * 128 + h]      = (sre * qr + sim * qi) * s2;
        OUTA[(long)r * 1536 + k * 128 + 64 + h] = (sim * qr - sre * qi) * s2;
    }
}

// ya[r, k*192+j] = (Ys+hw*Yd)[j] * silu((Ys+hw*Yd)[192+j]) per k-group of 384
__global__ void combine_k(const float* __restrict__ Ys, const float* __restrict__ Yd,
                          const float* __restrict__ hw, float* __restrict__ ya,
                          int rows)
{
    const long n = (long)rows * 2304;
    for (long t = (long)blockIdx.x * blockDim.x + threadIdx.x; t < n;
         t += (long)gridDim.x * blockDim.x) {
        const long r = t / 2304;
        const int cj = (int)(t % 2304);
        const int k = cj / 192, j = cj % 192;
        const long base = r * 4608 + (long)k * 384;
        const float hwk = hw[k];
        const float yv = Ys[base + j]       + hwk * Yd[base + j];
        const float yg = Ys[base + 192 + j] + hwk * Yd[base + 192 + j];
        ya[t] = yv * yg * sigmoidf(yg);
    }
}

// ---------------------------------------------------------------------------
extern "C" void kernel_launch(void* const* d_in, const int* in_sizes, int n_in,
                              void* d_out, int out_size, void* d_ws, size_t ws_size,
                              hipStream_t stream)
{
    float* out = (float*)d_out;   // reference output dtype is float32!
    const dim3 blk(256);

    // ---- tripwire: verify input ordering/sizes; mismatch -> sentinel 3000+i
    const int expSz[16] = {12582912, 599040, 3120, 589824, 768, 12, 12,
                           294912, 294912, 768, 9216, 12, 147456, 884736,
                           12, 1769472};
    int bad = -1;
    if (n_in != 16) bad = 99;
    else { for (int i = 0; i < 16; i++) if (in_sizes[i] != expSz[i]) { bad = i; break; } }
    if (out_size != 12582912 && bad < 0) bad = 98;
    if (bad >= 0) {
        fillf_k<<<dim3(2048), blk, 0, stream>>>(out, out_size, 3000.f + bad);
        return;
    }

    const float* x     = (const float*)d_in[0];
    const float* W_mem = (const float*)d_in[1];
    const float* convk = (const float*)d_in[2];
    const float* W_q   = (const float*)d_in[3];
    const float* theta = (const float*)d_in[4];
    const float* decay = (const float*)d_in[5];
    const float* ssc   = (const float*)d_in[6];
    const float* W_re  = (const float*)d_in[7];
    const float* W_im  = (const float*)d_in[8];
    const float* nsc   = (const float*)d_in[9];
    const float* Wg    = (const float*)d_in[10];
    const float* bg    = (const float*)d_in[11];
    const float* W_dn  = (const float*)d_in[12];
    const float* W_up  = (const float*)d_in[13];
    const float* hw    = (const float*)d_in[14];
    const float* W_out = (const float*)d_in[15];

    // ---- workspace plan ladder (all f32)
    const int nCfg = 5;
    const int cfgL[nCfg] = {2048, 1024, 512, 256, 128};
    const int cfgR[nCfg] = {512,  256,  128, 64,  64};
    size_t o[12];
    auto plan = [&](int Ls, int Rs, size_t* oo) -> size_t {
        size_t off = 0;
        auto al = [&](size_t bytes) {
            size_t cur = off; off = (off + bytes + 255) & ~(size_t)255; return cur;
        };
        oo[0]  = al(4);                              // md
        oo[1]  = al((size_t)NCH_ * 4);               // carry
        oo[2]  = al((size_t)(Ls + 3) * ZC_ * 4);     // Zs (with 3-row halo)
        oo[3]  = al((size_t)Ls * ZC_ * 4);           // ZC
        oo[4]  = al((size_t)Ls * 768 * 4);           // Q
        oo[5]  = al((size_t)Ls * K_ * 4);            // G
        oo[6]  = al((size_t)Ls * 192 * 4);           // LAT
        oo[7]  = al((size_t)Ls * NCH_ * 4);          // MERG
        oo[8]  = al((size_t)Ls * 1536 * 4);          // OUTA
        oo[9]  = al((size_t)Rs * 4608 * 4);          // Ysum
        oo[10] = al((size_t)Rs * 4608 * 4);          // Ydir
        oo[11] = al((size_t)Rs * 2304 * 4);          // ya
        return off;
    };
    int LSEC = -1, RS = 0;
    for (int c = 0; c < nCfg; c++) {
        size_t t = plan(cfgL[c], cfgR[c], o);
        if (t + 4096 <= ws_size) { LSEC = cfgL[c]; RS = cfgR[c]; break; }
    }
    if (LSEC < 0) {
        fillf_k<<<dim3(2048), blk, 0, stream>>>(out, (long)out_size, 1000.f);
        return;
    }

    char* ws = (char*)d_ws;
    int*   md    = (int*)(ws + o[0]);
    float* carry = (float*)(ws + o[1]);
    float* Zs    = (float*)(ws + o[2]);
    float* ZCo   = (float*)(ws + o[3]);
    float* Qp    = (float*)(ws + o[4]);
    float* Gp    = (float*)(ws + o[5]);
    float* LATp  = (float*)(ws + o[6]);
    float* MERG  = (float*)(ws + o[7]);
    float* OUTA  = (float*)(ws + o[8]);
    float* Ysum  = (float*)(ws + o[9]);
    float* Ydir  = (float*)(ws + o[10]);
    float* yap   = (float*)(ws + o[11]);

    auto cdiv = [](long a, long b) { return (int)((a + b - 1) / b); };
    auto gsz  = [&](long n) { int g = cdiv(n, 256); return g > 8192 ? 8192 : g; };

    probe_k<<<dim3(1), dim3(64), 0, stream>>>((const unsigned*)ssc, md);

    const int nsec = L_ / LSEC;
    for (int b = 0; b < B_; b++) {
        // zero the cumsum carry at batch start
        fillf_k<<<dim3(7), blk, 0, stream>>>(carry, NCH_, 0.f);

        for (int s = 0; s < nsec; s++) {
            const int l0 = s * LSEC;

            // ---- Zs rows cover global l in [l0-3, l0+LSEC)
            int pad = (l0 == 0) ? 3 : 0;               // rows with l<0 -> zero
            if (pad) fillf_k<<<dim3(16), blk, 0, stream>>>(Zs, (long)pad * ZC_, 0.f);
            {
                const int rows = LSEC + 3 - pad;
                const float* Axp = x + ((long)b * L_ + (l0 - 3 + pad)) * 768;
                ngemm<false><<<dim3(gsz((long)rows * ZC_), 1), blk, 0, stream>>>(
                    Axp, W_mem, Zs + (long)pad * ZC_,
                    rows, ZC_, 768, 768, ZC_, ZC_, 0, 0, 0);
            }
            conv_k<<<dim3(gsz((long)LSEC * ZC_)), blk, 0, stream>>>(Zs, convk, ZCo, LSEC);

            // ---- section projections (explicit pre-offset pointers)
            const float* xs = x + ((long)b * L_ + l0) * 768;
            ngemm<false><<<dim3(gsz((long)LSEC * 768), 1), blk, 0, stream>>>(
                xs, W_q, Qp, LSEC, 768, 768, 768, 768, 768, 0, 0, 0);
            ngemm<false><<<dim3(gsz((long)LSEC * K_), 1), blk, 0, stream>>>(
                xs, Wg, Gp, LSEC, K_, 768, 768, K_, K_, 0, 0, 0);
            ngemm<false><<<dim3(gsz((long)LSEC * 192), 1), blk, 0, stream>>>(
                xs, W_dn, LATp, LSEC, 192, 768, 768, 192, 192, 0, 0, 0);

            // ---- elementwise -> MERG; sequential cumsum with carry
            elem_k<<<dim3(gsz((long)LSEC * NCH_)), blk, 0, stream>>>(
                ZCo, theta, decay, ssc, MERG, LSEC, l0);
            cumsum_k<<<dim3(cdiv(NCH_, 64)), dim3(64), 0, stream>>>(MERG, carry, LSEC);

            // ---- outA
            outa_k<<<dim3(gsz((long)LSEC * K_ * H_)), blk, 0, stream>>>(
                MERG, Qp, Gp, nsc, bg, OUTA, LSEC);

            // ---- stages 3+4 in row slabs
            for (int r0 = 0; r0 < LSEC; r0 += RS) {
                // y_spec: Ysum[r, k*384+n] = outRE@W_re[k] + outIM@W_im[k]
                ngemm<false><<<dim3(gsz((long)RS * 384), 12), blk, 0, stream>>>(
                    OUTA + (long)r0 * 1536, W_re, Ysum,
                    RS, 384, 64, 1536, 384, 4608,
                    128, (long)64 * 384, 384);
                ngemm<true><<<dim3(gsz((long)RS * 384), 12), blk, 0, stream>>>(
                    OUTA + (long)r0 * 1536 + 64, W_im, Ysum,
                    RS, 384, 64, 1536, 384, 4608,
                    128, (long)64 * 384, 384);
                // y_dir: Ydir = LAT @ W_up
                ngemm<false><<<dim3(gsz((long)RS * 4608), 1), blk, 0, stream>>>(
                    LATp + (long)r0 * 192, W_up, Ydir,
                    RS, 4608, 192, 192, 4608, 4608, 0, 0, 0);
                // combine with highway + silu
                combine_k<<<dim3(gsz((long)RS * 2304)), blk, 0, stream>>>(
                    Ysum, Ydir, hw, yap, RS);
                // out = ya @ W_out  (f32 store)
                ngemm<false><<<dim3(gsz((long)RS * 768), 1), blk, 0, stream>>>(
                    yap, W_out, out + ((long)b * L_ + l0 + r0) * 768,
                    RS, 768, 2304, 2304, 768, 768, 0, 0, 0);
            }
        }
    }

    // dtype tripwire: overwrite with 4000+mode if inputs weren't f32
    guard_k<<<dim3(2048), blk, 0, stream>>>(md, out, (long)out_size);
}

// Round 9
// 12928.839 us; speedup vs baseline: 3.3114x; 3.3114x over previous
//
#include <hip/hip_runtime.h>
#include <hip/hip_bf16.h>

typedef __hip_bfloat16 bf16;

#define B_    4
#define L_    4096
#define K_    12
#define H_    64
#define ZC_   780        /* MEM + K */
#define CH2_  128        /* scan chunks */
#define CL2_  32         /* rows per chunk = L_/CH2_ */

__device__ __forceinline__ float softplusf(float x){ return log1pf(__expf(x)); }
__device__ __forceinline__ float sigmoidf(float x){ return 1.f / (1.f + __expf(-x)); }
__device__ __forceinline__ bf16 f2b(float v){ return __float2bfloat16(v); }
__device__ __forceinline__ float ldval(const float* p){ return *p; }
__device__ __forceinline__ float ldval(const bf16*  p){ return __bfloat162float(*p); }
__device__ __forceinline__ void  stval(float* p, float v){ *p = v; }
__device__ __forceinline__ void  stval(bf16*  p, float v){ *p = f2b(v); }

// dtype probe: score_scale == ones; f32 1.0 -> 0x3F800000
__global__ void probe_k(const unsigned* __restrict__ ss, int* __restrict__ md)
{
    if (threadIdx.x == 0 && blockIdx.x == 0) {
        unsigned w = ss[0];
        int m = 0;
        if      (w == 0x3F803F80u) m = 1;
        else if (w == 0x3C003C00u) m = 2;
        else if (w == 0x00000000u) m = 3;
        else if (w != 0x3F800000u) m = 4;
        md[0] = m;
    }
}

__global__ void fillf_k(float* __restrict__ p, long n, float v)
{
    for (long i = (long)blockIdx.x * blockDim.x + threadIdx.x; i < n;
         i += (long)gridDim.x * blockDim.x) p[i] = v;
}
__global__ void guard_k(const int* __restrict__ md, float* __restrict__ p, long n)
{
    const int m = *md;
    if (m == 0) return;
    for (long i = (long)blockIdx.x * blockDim.x + threadIdx.x; i < n;
         i += (long)gridDim.x * blockDim.x) p[i] = 4000.f + m;
}

// ---------------------------------------------------------------------------
// Tiled GEMM: C[M,N] = A[M,Kd] @ B[Kd,N] (+C if ACC). BM=BN=128, BK=16,
// 256 threads, 8x8 micro-tile. Kd must be a multiple of 16. Batched via
// blockIdx.z with ELEMENT strides sA/sB/sC.
// ---------------------------------------------------------------------------
template<typename TA, typename TB, typename TC, bool ACC>
__global__ __launch_bounds__(256) void gemm_k(
    const TA* __restrict__ Ag, const TB* __restrict__ Bg, TC* __restrict__ Cg,
    int M, int N, int Kd, int lda, int ldb, int ldc,
    long sA, long sB, long sC)
{
    __shared__ float As[16][128];
    __shared__ float Bs[16][128];
    const TA* A = Ag + (long)blockIdx.z * sA;
    const TB* B = Bg + (long)blockIdx.z * sB;
    TC*       C = Cg + (long)blockIdx.z * sC;
    const int m0 = blockIdx.y * 128, n0 = blockIdx.x * 128;
    const int tid = threadIdx.x;
    const int tx = tid & 15, ty = tid >> 4;

    float acc[8][8];
    #pragma unroll
    for (int i = 0; i < 8; i++)
        #pragma unroll
        for (int j = 0; j < 8; j++) acc[i][j] = 0.f;

    for (int k0 = 0; k0 < Kd; k0 += 16) {
        #pragma unroll
        for (int i = 0; i < 8; i++) {               // A tile: 128 x 16
            int idx = tid * 8 + i;
            int r = idx >> 4, c = idx & 15;
            int gm = m0 + r;
            float v = 0.f;
            if (gm < M) v = ldval(&A[(long)gm * lda + (k0 + c)]);
            As[c][r] = v;
        }
        #pragma unroll
        for (int i = 0; i < 8; i++) {               // B tile: 16 x 128
            int idx = tid * 8 + i;
            int r = idx >> 7, c = idx & 127;
            int gn = n0 + c;
            float v = 0.f;
            if (gn < N) v = ldval(&B[(long)(k0 + r) * ldb + gn]);
            Bs[r][c] = v;
        }
        __syncthreads();
        #pragma unroll
        for (int kk = 0; kk < 16; kk++) {
            float a[8], b[8];
            #pragma unroll
            for (int i = 0; i < 8; i++) a[i] = As[kk][ty * 8 + i];
            #pragma unroll
            for (int j = 0; j < 8; j++) b[j] = Bs[kk][tx * 8 + j];
            #pragma unroll
            for (int i = 0; i < 8; i++)
                #pragma unroll
                for (int j = 0; j < 8; j++) acc[i][j] += a[i] * b[j];
        }
        __syncthreads();
    }
    #pragma unroll
    for (int i = 0; i < 8; i++) {
        int gm = m0 + ty * 8 + i;
        if (gm >= M) continue;
        #pragma unroll
        for (int j = 0; j < 8; j++) {
            int gn = n0 + tx * 8 + j;
            if (gn >= N) continue;
            long cix = (long)gm * ldc + gn;
            float v = acc[i][j];
            if (ACC) v += ldval(&C[cix]);
            stval(&C[cix], v);
        }
    }
}

// Wup2 = W_up * highway[col/384]
__global__ void packup_k(const float* __restrict__ Wup, const float* __restrict__ hw,
                         float* __restrict__ Wup2)
{
    const int n = 192 * 4608;
    for (int i = blockIdx.x * blockDim.x + threadIdx.x; i < n;
         i += gridDim.x * blockDim.x)
        Wup2[i] = Wup[i] * hw[(i % 4608) / 384];
}

// ---------------------------------------------------------------------------
// Fused scan. Zs row j holds Z at l=j-3 (rows 0..2 are the zero halo), so
// conv at l reads Zs[l+i], i=0..3. Pass1 (FINAL=false): per-(chunk,k) sums
// into csum[k][ch][129] = [den | re*64 | im*64]. Pass3 (FINAL=true): walk
// rows with exclusive-prefix init, emit OUTA[l, k*128 + {h,64+h}].
// grid (CH2_, K_), 64 threads (lane = h).
// ---------------------------------------------------------------------------
template<bool FINAL>
__global__ __launch_bounds__(64) void scan_k(
    const float* __restrict__ Zs, const float* __restrict__ Q,
    const float* __restrict__ G, const float* __restrict__ convk,
    const float* __restrict__ theta, const float* __restrict__ decay,
    const float* __restrict__ ssc, const float* __restrict__ nsc,
    const float* __restrict__ bg, float* __restrict__ csum,
    float* __restrict__ OUTA)
{
    const int ch = blockIdx.x, k = blockIdx.y, h = threadIdx.x;
    const int col = k * 64 + h, scol = 768 + k;
    const int l0 = ch * CL2_;

    const float ck0 = convk[col],  ck1 = convk[ZC_ + col];
    const float ck2 = convk[2 * ZC_ + col], ck3 = convk[3 * ZC_ + col];
    const float cs0 = convk[scol], cs1 = convk[ZC_ + scol];
    const float cs2 = convk[2 * ZC_ + scol], cs3 = convk[3 * ZC_ + scol];

    const float th    = softplusf(theta[k * 64 + h]) + 0.001f;
    const float slope = softplusf(decay[k]);
    const float sscal = ssc[k];
    const float ns    = FINAL ? nsc[k * 64 + h] : 0.f;
    const float bgk   = FINAL ? bg[k] : 0.f;
    const int   kq    = k >> 1;

    const long cb = ((long)k * CH2_ + ch) * 129;
    float dacc = 0.f, racc = 0.f, iacc = 0.f;
    if (FINAL) { dacc = csum[cb]; racc = csum[cb + 1 + h]; iacc = csum[cb + 65 + h]; }

    for (int p = 0; p < CL2_; p++) {
        const int l = l0 + p;
        const float* zr = Zs + (long)l * ZC_;
        const float kv = ck0 * zr[col]  + ck1 * zr[ZC_ + col]
                       + ck2 * zr[2 * ZC_ + col] + ck3 * zr[3 * ZC_ + col];
        const float sr = cs0 * zr[scol] + cs1 * zr[ZC_ + scol]
                       + cs2 * zr[2 * ZC_ + scol] + cs3 * zr[3 * ZC_ + scol];
        const float lp = fminf(fmaxf(sscal * sr, -20.f), 20.f);
        const float pw = __expf(lp - slope * (float)(L_ - 1 - l));
        const float phi = tanhf(kv) * th;
        float sn, cn; __sincosf(phi, &sn, &cn);
        dacc += pw; racc += kv * pw * cn; iacc += kv * pw * sn;

        if (FINAL) {
            const float invd = 1.f / fmaxf(dacc, 1e-4f);
            const float sre = racc * invd, sim = iacc * invd;
            const float qr = Q[(long)l * 768 + (kq * 64 + h) * 2];
            const float qi = Q[(long)l * 768 + (kq * 64 + h) * 2 + 1];
            const float gate = sigmoidf(G[(long)l * K_ + k] + bgk);
            const float s2 = ns * gate;
            OUTA[(long)l * 1536 + k * 128 + h]      = (sre * qr + sim * qi) * s2;
            OUTA[(long)l * 1536 + k * 128 + 64 + h] = (sim * qr - sre * qi) * s2;
        }
    }
    if (!FINAL) {
        if (h == 0) csum[cb] = dacc;
        csum[cb + 1 + h]  = racc;
        csum[cb + 65 + h] = iacc;
    }
}

// exclusive prefix over the 128 chunks, per (k, entry 0..128)
__global__ void scan2_k(float* __restrict__ csum)
{
    const int k = blockIdx.x;
    const int t = threadIdx.x;
    if (t >= 129) return;
    float run = 0.f;
    for (int c = 0; c < CH2_; c++) {
        const long ix = ((long)k * CH2_ + c) * 129 + t;
        float v = csum[ix]; csum[ix] = run; run += v;
    }
}

// ya[r, k*192+j] = yv * silu(yg), yv = Ys[r, k*384+j], yg = Ys[r, k*384+192+j]
__global__ void combine_k(const float* __restrict__ Ys, float* __restrict__ ya,
                          int rows)
{
    const long n = (long)rows * 2304;
    for (long t = (long)blockIdx.x * blockDim.x + threadIdx.x; t < n;
         t += (long)gridDim.x * blockDim.x) {
        const long r = t / 2304;
        const int cj = (int)(t % 2304);
        const int k = cj / 192, j = cj % 192;
        const long base = r * 4608 + (long)k * 384;
        const float yv = Ys[base + j];
        const float yg = Ys[base + 192 + j];
        ya[t] = yv * yg * sigmoidf(yg);
    }
}

// ---------------------------------------------------------------------------
extern "C" void kernel_launch(void* const* d_in, const int* in_sizes, int n_in,
                              void* d_out, int out_size, void* d_ws, size_t ws_size,
                              hipStream_t stream)
{
    float* out = (float*)d_out;   // f32 output (verified r8)
    const dim3 blk(256);

    // tripwire: input ordering/sizes
    const int expSz[16] = {12582912, 599040, 3120, 589824, 768, 12, 12,
                           294912, 294912, 768, 9216, 12, 147456, 884736,
                           12, 1769472};
    int bad = -1;
    if (n_in != 16) bad = 99;
    else { for (int i = 0; i < 16; i++) if (in_sizes[i] != expSz[i]) { bad = i; break; } }
    if (out_size != 12582912 && bad < 0) bad = 98;
    if (bad >= 0) {
        fillf_k<<<dim3(2048), blk, 0, stream>>>(out, out_size, 3000.f + bad);
        return;
    }

    const float* x     = (const float*)d_in[0];
    const float* W_mem = (const float*)d_in[1];
    const float* convk = (const float*)d_in[2];
    const float* W_q   = (const float*)d_in[3];
    const float* theta = (const float*)d_in[4];
    const float* decay = (const float*)d_in[5];
    const float* ssc   = (const float*)d_in[6];
    const float* W_re  = (const float*)d_in[7];
    const float* W_im  = (const float*)d_in[8];
    const float* nsc   = (const float*)d_in[9];
    const float* Wg    = (const float*)d_in[10];
    const float* bg    = (const float*)d_in[11];
    const float* W_dn  = (const float*)d_in[12];
    const float* W_up  = (const float*)d_in[13];
    const float* hw    = (const float*)d_in[14];
    const float* W_out = (const float*)d_in[15];

    // ---- workspace plan: fixed full-batch buffers + RS slab ladder
    size_t o[10];
    auto plan = [&](int Rs, size_t* oo) -> size_t {
        size_t off = 0;
        auto al = [&](size_t bytes) {
            size_t cur = off; off = (off + bytes + 255) & ~(size_t)255; return cur;
        };
        oo[0] = al(4);                                  // md
        oo[1] = al((size_t)K_ * CH2_ * 129 * 4);        // csum
        oo[2] = al((size_t)(L_ + 3) * ZC_ * 4);         // Zs (3-row halo)
        oo[3] = al((size_t)L_ * 768 * 4);               // Q
        oo[4] = al((size_t)L_ * K_ * 4);                // G
        oo[5] = al((size_t)L_ * 192 * 4);               // LAT
        oo[6] = al((size_t)L_ * 1536 * 4);              // OUTA
        oo[7] = al((size_t)192 * 4608 * 4);             // Wup2
        oo[8] = al((size_t)Rs * 4608 * 4);              // Ysum slab
        oo[9] = al((size_t)Rs * 2304 * 4);              // ya slab
        return off;
    };
    const int nCfg = 4;
    const int cfgR[nCfg] = {1024, 512, 256, 128};
    int RS = -1;
    for (int c = 0; c < nCfg; c++) {
        size_t t = plan(cfgR[c], o);
        if (t + 4096 <= ws_size) { RS = cfgR[c]; break; }
    }
    if (RS < 0) {
        fillf_k<<<dim3(2048), blk, 0, stream>>>(out, (long)out_size, 1000.f);
        return;
    }

    char* ws = (char*)d_ws;
    int*   md   = (int*)(ws + o[0]);
    float* csum = (float*)(ws + o[1]);
    float* Zs   = (float*)(ws + o[2]);
    float* Qp   = (float*)(ws + o[3]);
    float* Gp   = (float*)(ws + o[4]);
    float* LATp = (float*)(ws + o[5]);
    float* OUTA = (float*)(ws + o[6]);
    float* Wup2 = (float*)(ws + o[7]);
    float* Ysum = (float*)(ws + o[8]);
    float* yap  = (float*)(ws + o[9]);

    auto cdiv = [](long a, long b) { return (int)((a + b - 1) / b); };
    auto gsz  = [&](long n) { int g = cdiv(n, 256); return g > 8192 ? 8192 : g; };

    probe_k<<<dim3(1), dim3(64), 0, stream>>>((const unsigned*)ssc, md);
    packup_k<<<dim3(1024), blk, 0, stream>>>(W_up, hw, Wup2);
    // zero the 3 halo rows of Zs once (never overwritten)
    fillf_k<<<dim3(16), blk, 0, stream>>>(Zs, 3 * ZC_, 0.f);

    for (int b = 0; b < B_; b++) {
        const float* xb = x + (long)b * L_ * 768;

        // projections (tiled): Z (into halo-offset), Q, G, LAT
        gemm_k<float, float, float, false><<<dim3(7, 32), blk, 0, stream>>>(
            xb, W_mem, Zs + 3 * ZC_, L_, ZC_, 768, 768, ZC_, ZC_, 0, 0, 0);
        gemm_k<float, float, float, false><<<dim3(6, 32), blk, 0, stream>>>(
            xb, W_q, Qp, L_, 768, 768, 768, 768, 768, 0, 0, 0);
        gemm_k<float, float, float, false><<<dim3(1, 32), blk, 0, stream>>>(
            xb, Wg, Gp, L_, K_, 768, 768, K_, K_, 0, 0, 0);
        gemm_k<float, float, float, false><<<dim3(2, 32), blk, 0, stream>>>(
            xb, W_dn, LATp, L_, 192, 768, 768, 192, 192, 0, 0, 0);

        // fused chunked scan (conv+elem inline), 3 passes -> OUTA
        scan_k<false><<<dim3(CH2_, K_), dim3(64), 0, stream>>>(
            Zs, nullptr, nullptr, convk, theta, decay, ssc, nsc, bg, csum, nullptr);
        scan2_k<<<dim3(K_), dim3(192), 0, stream>>>(csum);
        scan_k<true><<<dim3(CH2_, K_), dim3(64), 0, stream>>>(
            Zs, Qp, Gp, convk, theta, decay, ssc, nsc, bg, csum, OUTA);

        // stages 3+4 in row slabs
        for (int r0 = 0; r0 < L_; r0 += RS) {
            // y_spec: Ysum[r, k*384+n] = outRE@W_re[k] + outIM@W_im[k]
            gemm_k<float, float, float, false><<<dim3(3, RS / 128, 12), blk, 0, stream>>>(
                OUTA + (long)r0 * 1536, W_re, Ysum,
                RS, 384, 64, 1536, 384, 4608, 128, (long)64 * 384, 384);
            gemm_k<float, float, float, true><<<dim3(3, RS / 128, 12), blk, 0, stream>>>(
                OUTA + (long)r0 * 1536 + 64, W_im, Ysum,
                RS, 384, 64, 1536, 384, 4608, 128, (long)64 * 384, 384);
            // Ysum += LAT @ Wup2   (highway folded into Wup2)
            gemm_k<float, float, float, true><<<dim3(36, RS / 128), blk, 0, stream>>>(
                LATp + (long)r0 * 192, Wup2, Ysum,
                RS, 4608, 192, 192, 4608, 4608, 0, 0, 0);
            // silu combine -> ya
            combine_k<<<dim3(gsz((long)RS * 2304)), blk, 0, stream>>>(Ysum, yap, RS);
            // out = ya @ W_out (f32)
            gemm_k<float, float, float, false><<<dim3(6, RS / 128), blk, 0, stream>>>(
                yap, W_out, out + ((long)b * L_ + r0) * 768,
                RS, 768, 2304, 2304, 768, 768, 0, 0, 0);
        }
    }

    guard_k<<<dim3(2048), blk, 0, stream>>>(md, out, (long)out_size);
}